// Round 14
// baseline (373.449 us; speedup 1.0000x reference)
//
#include <hip/hip_runtime.h>
#include <math.h>

constexpr int Nn = 16384;
constexpr size_t NS = (size_t)Nn * 16;      // dwords per channel plane of npts
constexpr int GPW = 4;                      // 4-pt groups per wave; 16 pts/wave; 64/block

// ---- DPP helpers (rows of 16, pure VALU) ----
template <int CTRL>
__device__ __forceinline__ float dpp_f(float x) {
    return __int_as_float(
        __builtin_amdgcn_update_dpp(0, __float_as_int(x), CTRL, 0xF, 0xF, false));
}
__device__ __forceinline__ float rsum16(float v) {
    v += dpp_f<0x128>(v); v += dpp_f<0x124>(v);
    v += dpp_f<0x122>(v); v += dpp_f<0x121>(v);
    return v;
}
__device__ __forceinline__ float rmax16(float v) {
    v = fmaxf(v, dpp_f<0x128>(v)); v = fmaxf(v, dpp_f<0x124>(v));
    v = fmaxf(v, dpp_f<0x122>(v)); v = fmaxf(v, dpp_f<0x121>(v));
    return v;
}

// LDS-visibility barrier (no vmcnt drain): prefetched global loads stay in flight.
#define BAR() do { asm volatile("s_waitcnt lgkmcnt(0)" ::: "memory"); \
    __builtin_amdgcn_s_barrier(); asm volatile("" ::: "memory"); } while (0)

// ====== Fused, barrier-free-loop kernel ======
// Block = 4 waves = 64 points. Phase Q (all 256 threads) computes qk/pp for the
// block's 64 points into qk_lds; ONE barrier; then each wave independently
// streams its 16 points (4 groups of 4) across ALL 64 channels: lane = (nn,s),
// logit -> DPP softmax -> fused vbar+Wv matvec. No in-loop barriers; liveness
// prefetch keeps HBM loads in flight under compute.
__global__ __launch_bounds__(256, 4) void attn_fused_kernel(
    const float* __restrict__ xyz, const float* __restrict__ nxyz,
    const float* __restrict__ points, const float* __restrict__ npts,
    const float* __restrict__ Wk, const float* __restrict__ Wv,
    const float* __restrict__ Wp, float* __restrict__ out)
{
    __shared__ float wvT[67 * 68];              // [c][o], stride 68
    __shared__ float qk_lds[64 * 68];           // [pt_local][64 qk + 4 pp]

    const int tid = threadIdx.x;
    const int w = tid >> 6;
    const int l = tid & 63;
    const int s = l & 15;
    const int nn = l >> 4;
    const int gptbase = blockIdx.x * 64;        // 64-pt chunk, never straddles b
    const int b = gptbase >> 14;
    const int ngbase = gptbase & (Nn - 1);
    const int nw = ngbase + w * 16;             // this wave's first point col

    // ---- one-time Wv transpose stage ----
    for (int idx = tid; idx < 64 * 67; idx += 256) {
        const int o = idx / 67, c = idx - o * 67;
        wvT[c * 68 + o] = Wv[idx];
    }

    // ---- group-0 prefetch FIRST: hides under phase Q ----
    const float* npb0 = npts + (size_t)(b * 64) * NS + (size_t)nw * 16 + l;  // +c*NS +g*64
    float npv[64];
#pragma unroll
    for (int c = 0; c < 64; ++c) npv[c] = npb0[(size_t)c * NS];
    float nxa = nxyz[((size_t)(b * 3 + 0) * Nn + nw) * 16 + l];
    float nxb = nxyz[((size_t)(b * 3 + 1) * Nn + nw) * 16 + l];
    float nxc = nxyz[((size_t)(b * 3 + 2) * Nn + nw) * 16 + l];
    float xa = xyz[(size_t)(b * 3 + 0) * Nn + nw + nn];
    float xb = xyz[(size_t)(b * 3 + 1) * Nn + nw + nn];
    float xc = xyz[(size_t)(b * 3 + 2) * Nn + nw + nn];

    // ---- phase Q: qk = Wk^T (q*scale), pp = Wp^T qk for all 64 block points ----
    // thread = (pt_local = w*16 + (l&15), quarter = l>>4)
    {
        const int quarter = l >> 4;
        const int ptl = w * 16 + (l & 15);
        const int n = ngbase + ptl;

        float qk[16];
#pragma unroll
        for (int k = 0; k < 16; ++k) qk[k] = 0.f;

        const float* prow = points + (size_t)b * 64 * Nn + n;
        const float* wkq = Wk + 16 * quarter;
#pragma unroll 4
        for (int c = 0; c < 64; ++c) {
            const float qv = prow[(size_t)c * Nn];
            const float4 w0 = *(const float4*)(wkq + c * 64 + 0);
            const float4 w1 = *(const float4*)(wkq + c * 64 + 4);
            const float4 w2 = *(const float4*)(wkq + c * 64 + 8);
            const float4 w3 = *(const float4*)(wkq + c * 64 + 12);
            qk[0]  = fmaf(qv, w0.x, qk[0]);  qk[1]  = fmaf(qv, w0.y, qk[1]);
            qk[2]  = fmaf(qv, w0.z, qk[2]);  qk[3]  = fmaf(qv, w0.w, qk[3]);
            qk[4]  = fmaf(qv, w1.x, qk[4]);  qk[5]  = fmaf(qv, w1.y, qk[5]);
            qk[6]  = fmaf(qv, w1.z, qk[6]);  qk[7]  = fmaf(qv, w1.w, qk[7]);
            qk[8]  = fmaf(qv, w2.x, qk[8]);  qk[9]  = fmaf(qv, w2.y, qk[9]);
            qk[10] = fmaf(qv, w2.z, qk[10]); qk[11] = fmaf(qv, w2.w, qk[11]);
            qk[12] = fmaf(qv, w3.x, qk[12]); qk[13] = fmaf(qv, w3.y, qk[13]);
            qk[14] = fmaf(qv, w3.z, qk[14]); qk[15] = fmaf(qv, w3.w, qk[15]);
        }
#pragma unroll
        for (int k = 0; k < 16; ++k) qk[k] *= 0.125f;   // fold SCALE

        float p0 = 0.f, p1 = 0.f, p2 = 0.f, p3 = 0.f;
#pragma unroll
        for (int k = 0; k < 16; ++k) {
            const float4 wp4 = *(const float4*)(Wp + (16 * quarter + k) * 4);
            p0 = fmaf(qk[k], wp4.x, p0);
            p1 = fmaf(qk[k], wp4.y, p1);
            p2 = fmaf(qk[k], wp4.z, p2);
            p3 = fmaf(qk[k], wp4.w, p3);
        }
        p0 += __shfl_xor(p0, 16); p0 += __shfl_xor(p0, 32);
        p1 += __shfl_xor(p1, 16); p1 += __shfl_xor(p1, 32);
        p2 += __shfl_xor(p2, 16); p2 += __shfl_xor(p2, 32);
        p3 += __shfl_xor(p3, 16); p3 += __shfl_xor(p3, 32);

        float* orow = qk_lds + ptl * 68 + 16 * quarter;
        ((float4*)orow)[0] = make_float4(qk[0],  qk[1],  qk[2],  qk[3]);
        ((float4*)orow)[1] = make_float4(qk[4],  qk[5],  qk[6],  qk[7]);
        ((float4*)orow)[2] = make_float4(qk[8],  qk[9],  qk[10], qk[11]);
        ((float4*)orow)[3] = make_float4(qk[12], qk[13], qk[14], qk[15]);
        if (quarter == 0)
            *(float4*)(qk_lds + ptl * 68 + 64) = make_float4(p0, p1, p2, p3);
    }
    BAR();   // qk_lds + wvT visible; group-0 global prefetch still in flight

    // ---- main loop: fully wave-independent, zero barriers ----
#pragma unroll 1
    for (int g = 0; g < GPW; ++g) {
        const int ng = nw + 4 * g;

        // relative position for this lane's (nn, s); nx dies here
        const float d0 = xa - nxa, d1 = xb - nxb, d2 = xc - nxc;
        const float dn = sqrtf(d0 * d0 + d1 * d1 + d2 * d2);

        // prefetch next group's nx/xx immediately (longest use distance);
        // clamp on last group -> redundant cached reload, keeps code uniform
        {
            const int gn = (g + 1 < GPW) ? g + 1 : g;
            const size_t go = (size_t)gn * 64;
            nxa = nxyz[((size_t)(b * 3 + 0) * Nn + nw) * 16 + go + l];
            nxb = nxyz[((size_t)(b * 3 + 1) * Nn + nw) * 16 + go + l];
            nxc = nxyz[((size_t)(b * 3 + 2) * Nn + nw) * 16 + go + l];
            xa = xyz[(size_t)(b * 3 + 0) * Nn + nw + 4 * gn + nn];
            xb = xyz[(size_t)(b * 3 + 1) * Nn + nw + 4 * gn + nn];
            xc = xyz[(size_t)(b * 3 + 2) * Nn + nw + 4 * gn + nn];
        }

        // ---- logit = qk . np + pp . pos  (qk: LDS b128 broadcast, 4 rows/instr) ----
        const float* qrow = qk_lds + (w * 16 + 4 * g + nn) * 68;
        float l0 = 0.f, l1 = 0.f, l2 = 0.f, l3 = 0.f;
#pragma unroll
        for (int j = 0; j < 16; ++j) {
            const float4 qv = ((const float4*)qrow)[j];
            l0 = fmaf(qv.x, npv[4 * j + 0], l0);
            l1 = fmaf(qv.y, npv[4 * j + 1], l1);
            l2 = fmaf(qv.z, npv[4 * j + 2], l2);
            l3 = fmaf(qv.w, npv[4 * j + 3], l3);
        }
        const float4 pp = ((const float4*)qrow)[16];
        float logit = (l0 + l1) + (l2 + l3);
        logit += pp.x * d0 + pp.y * d1 + pp.z * d2 + pp.w * dn;
        // (bp term constant in s -> cancels in softmax)

        // ---- softmax over s (pure DPP in rows of 16) ----
        const float mx = rmax16(logit);
        const float e = __expf(logit - mx);
        const float se = rsum16(e);
        const float attn = e / se;

        // ---- fused vbar + Wv matvec; npv[c] prefetched in-place after last use ----
        const float* npb_n = npb0 + (size_t)((g + 1 < GPW) ? g + 1 : g) * 64;
        float4 oa = make_float4(0.f, 0.f, 0.f, 0.f);
#pragma unroll
        for (int c = 0; c < 64; ++c) {
            const float r = rsum16(attn * npv[c]);              // vbar[c, nn]
            const float4 wq = *(const float4*)&wvT[c * 68 + 4 * s];
            oa.x = fmaf(r, wq.x, oa.x);
            oa.y = fmaf(r, wq.y, oa.y);
            oa.z = fmaf(r, wq.z, oa.z);
            oa.w = fmaf(r, wq.w, oa.w);
            npv[c] = npb_n[(size_t)c * NS];                     // liveness prefetch
        }
        {   // tail channels 64..66 (= tmp d0,d1,d2); d dies here
            const float t0 = rsum16(attn * d0);
            const float t1 = rsum16(attn * d1);
            const float t2 = rsum16(attn * d2);
            const float4 wA = *(const float4*)&wvT[64 * 68 + 4 * s];
            const float4 wB = *(const float4*)&wvT[65 * 68 + 4 * s];
            const float4 wC = *(const float4*)&wvT[66 * 68 + 4 * s];
            oa.x += t0 * wA.x + t1 * wB.x + t2 * wC.x;
            oa.y += t0 * wA.y + t1 * wB.y + t2 * wC.y;
            oa.z += t0 * wA.z + t1 * wB.z + t2 * wC.z;
            oa.w += t0 * wA.w + t1 * wB.w + t2 * wC.w;
        }

        // stores: out[o = 4s+j][ng+nn] — 16 x 16B segments per instr
        float* ob = out + ((size_t)(b * 64 + 4 * s)) * Nn + ng + nn;
        ob[0]              = oa.x;
        ob[(size_t)Nn]     = oa.y;
        ob[(size_t)Nn * 2] = oa.z;
        ob[(size_t)Nn * 3] = oa.w;
    }
}

extern "C" void kernel_launch(void* const* d_in, const int* in_sizes, int n_in,
                              void* d_out, int out_size, void* d_ws, size_t ws_size,
                              hipStream_t stream) {
    const float* xyz    = (const float*)d_in[0];
    const float* nxyz   = (const float*)d_in[1];
    const float* points = (const float*)d_in[2];
    const float* npts   = (const float*)d_in[3];
    const float* Wk     = (const float*)d_in[4];
    const float* Wv     = (const float*)d_in[5];
    const float* Wp     = (const float*)d_in[6];
    // d_in[7] = bp — unused: constant-in-s logit shift cancels in softmax
    float* out = (float*)d_out;

    hipLaunchKernelGGL(attn_fused_kernel, dim3(1024), dim3(256), 0, stream,
                       xyz, nxyz, points, npts, Wk, Wv, Wp, out);
}